// Round 27
// baseline (143.306 us; speedup 1.0000x reference)
//
#include <hip/hip_runtime.h>
#include <cstddef>
#include <cstdint>

#define Bn 4
#define Tn 2048
#define Cn 768
#define Hn 12

typedef __attribute__((ext_vector_type(8))) short short8v;
typedef __attribute__((ext_vector_type(4))) float f32x4;
typedef unsigned short ushort_t;

struct us4 { unsigned short x, y, z, w; };

__device__ inline unsigned short f2bf(float f) {
  union { float f; unsigned u; } v; v.f = f;
  unsigned r = v.u + 0x7FFFu + ((v.u >> 16) & 1u);
  return (unsigned short)(r >> 16);
}
__device__ inline float bf2f(unsigned short u) {
  union { unsigned u; float f; } v; v.u = ((unsigned)u) << 16;
  return v.f;
}
__device__ inline unsigned cvt_pk_bf16(float lo, float hi) {
  unsigned r;
  asm("v_cvt_pk_bf16_f32 %0, %1, %2" : "=v"(r) : "v"(lo), "v"(hi));
  return r;
}

#define GLOAD_LDS16(gp, lp)                                                        \
  __builtin_amdgcn_global_load_lds(                                                \
      (const __attribute__((address_space(1))) void*)(gp),                         \
      (__attribute__((address_space(3))) void*)(lp), 16, 0, 0)

// -------- ONE prep launch: blocks 0..6143 -> x split; 6144..6719 -> W transposes --
__global__ __launch_bounds__(256) void prep_all(
    const float* __restrict__ x, ushort_t* __restrict__ xh, ushort_t* __restrict__ xl,
    const float* __restrict__ Wa, ushort_t* __restrict__ WaTh,
    ushort_t* __restrict__ WaTl, const float* __restrict__ Wp,
    ushort_t* __restrict__ WpT) {
  __shared__ float t[64][65];
  const int blk = blockIdx.x;
  const int tid = threadIdx.x;
  if (blk < 6144) {
    const int i = blk * 256 + tid;
    float4 v = reinterpret_cast<const float4*>(x)[i];
    us4 h;
    h.x = f2bf(v.x); h.y = f2bf(v.y); h.z = f2bf(v.z); h.w = f2bf(v.w);
    reinterpret_cast<us4*>(xh)[i] = h;
    const int row = (i << 2) / Cn;
    if ((row & (Tn - 1)) < 256) {
      us4 l;
      l.x = f2bf(v.x - bf2f(h.x)); l.y = f2bf(v.y - bf2f(h.y));
      l.z = f2bf(v.z - bf2f(h.z)); l.w = f2bf(v.w - bf2f(h.w));
      reinterpret_cast<us4*>(xl)[i] = l;
    }
    return;
  }
  const int id2 = blk - 6144;           // 0..575
  const int cx  = id2 % 48;             // 0..47
  const int ry  = id2 / 48;             // 0..11
  const bool split = (cx < 36);
  const float* W = split ? Wa : Wp;
  ushort_t* WTh  = split ? WaTh : WpT;
  const int cols = split ? 3 * Cn : Cn;
  const int c0   = (split ? cx : (cx - 36)) * 64;
  const int r0   = ry * 64;
  const int rows = Cn;
  const int c4 = (tid & 15) << 2;
  #pragma unroll
  for (int rr = 0; rr < 4; ++rr) {
    int r = rr * 16 + (tid >> 4);
    float4 v = *reinterpret_cast<const float4*>(&W[(size_t)(r0 + r) * cols + c0 + c4]);
    t[r][c4] = v.x; t[r][c4 + 1] = v.y; t[r][c4 + 2] = v.z; t[r][c4 + 3] = v.w;
  }
  __syncthreads();
  const int r4 = (tid & 15) << 2;
  #pragma unroll
  for (int cc = 0; cc < 4; ++cc) {
    int c = cc * 16 + (tid >> 4);
    float v0 = t[r4][c], v1 = t[r4 + 1][c], v2 = t[r4 + 2][c], v3 = t[r4 + 3][c];
    us4 h;
    h.x = f2bf(v0); h.y = f2bf(v1); h.z = f2bf(v2); h.w = f2bf(v3);
    *reinterpret_cast<us4*>(&WTh[(size_t)(c0 + c) * rows + r0 + r4]) = h;
    if (split) {
      us4 l;
      l.x = f2bf(v0 - bf2f(h.x)); l.y = f2bf(v1 - bf2f(h.y));
      l.z = f2bf(v2 - bf2f(h.z)); l.w = f2bf(v3 - bf2f(h.w));
      *reinterpret_cast<us4*>(&WaTl[(size_t)(c0 + c) * rows + r0 + r4]) = l;
    }
  }
}

// -------- FUSED qkv GEMM, XCD-BALANCED (12 comp blocks first + 144 plain per XCD).
//          attn_mask FOLDED INTO k (valid since mask>=0: relu(m*s)=m*relu(s)) -----
__global__ __launch_bounds__(256) void gemm_qkv_fused(
    const ushort_t* __restrict__ Ah, const ushort_t* __restrict__ Al,
    const ushort_t* __restrict__ Bh, const ushort_t* __restrict__ Bl,
    const float* __restrict__ lambda, const float* __restrict__ attn_mask,
    ushort_t* __restrict__ qhp, ushort_t* __restrict__ qlp,
    ushort_t* __restrict__ khp, ushort_t* __restrict__ klp,
    ushort_t* __restrict__ vtp) {
  constexpr int K = Cn, N = 3 * Cn;
  __shared__ ushort_t As[2][128 * 64];
  __shared__ ushort_t Bs[2][128 * 64];

  const int tid = threadIdx.x;
  const int w = tid >> 6;
  const int lane = tid & 63;
  const int lcol = lane & 15;
  const int g = lane >> 4;
  const int xcd = blockIdx.x & 7;
  const int pos = blockIdx.x >> 3;          // 0..155
  const bool comp = (pos < 12);
  int bm, bn;
  if (comp) {
    const int cid = xcd * 12 + pos;         // 0..95; byi == xcd
    bm = (xcd >> 1) * Tn + (xcd & 1) * 128;
    bn = (cid % 12) * 128;
  } else {
    const int pid = xcd * 144 + (pos - 12); // 0..1151
    bm = (pid / 18) * 128;
    bn = (pid % 18) * 128;
  }
  const int wr = (w >> 1) * 64;
  const int wc = (w & 1) * 64;
  const int srow = tid >> 3;
  const int sslot = tid & 7;

  f32x4 acc[4][4];
  #pragma unroll
  for (int m = 0; m < 4; ++m)
    #pragma unroll
    for (int n = 0; n < 4; ++n)
      acc[m][n] = (f32x4){0.f, 0.f, 0.f, 0.f};

  auto STAGE_A = [&](int k0, int buf, const ushort_t* A) {
    #pragma unroll
    for (int i = 0; i < 4; ++i) {
      const int row = i * 32 + srow;
      const int kslot = sslot ^ (row & 7);
      GLOAD_LDS16(A + (size_t)(bm + row) * K + k0 + kslot * 8,
                  (char*)As[buf] + (size_t)(i * 256 + tid) * 16);
    }
  };
  auto STAGE_B = [&](int k0, int buf, const ushort_t* B) {
    #pragma unroll
    for (int i = 0; i < 4; ++i) {
      const int row = i * 32 + srow;
      const int kslot = sslot ^ (row & 7);
      GLOAD_LDS16(B + (size_t)(bn + row) * K + k0 + kslot * 8,
                  (char*)Bs[buf] + (size_t)(i * 256 + tid) * 16);
    }
  };

  const int nt = K >> 6;
  if (!comp) {
    STAGE_A(0, 0, Ah); STAGE_B(0, 0, Bh);
    __syncthreads();
    for (int t = 0; t < nt; ++t) {
      const int cur = t & 1;
      if (t + 1 < nt) { STAGE_A((t + 1) << 6, cur ^ 1, Ah); STAGE_B((t + 1) << 6, cur ^ 1, Bh); }
      #pragma unroll
      for (int kk = 0; kk < 2; ++kk) {
        short8v a0[4], b0[4];
        #pragma unroll
        for (int m = 0; m < 4; ++m) {
          int row = wr + m * 16 + lcol;
          a0[m] = *reinterpret_cast<const short8v*>(
              (const char*)As[cur] + row * 128 + (((kk * 4 + g) ^ (row & 7)) << 4));
        }
        #pragma unroll
        for (int n = 0; n < 4; ++n) {
          int row = wc + n * 16 + lcol;
          b0[n] = *reinterpret_cast<const short8v*>(
              (const char*)Bs[cur] + row * 128 + (((kk * 4 + g) ^ (row & 7)) << 4));
        }
        #pragma unroll
        for (int m = 0; m < 4; ++m)
          #pragma unroll
          for (int n = 0; n < 4; ++n)
            acc[m][n] = __builtin_amdgcn_mfma_f32_16x16x32_bf16(a0[m], b0[n], acc[m][n], 0, 0, 0);
      }
      __syncthreads();
    }
  } else {
    for (int t = 0; t < nt; ++t) {
      const int k0 = t << 6;
      __syncthreads();
      STAGE_A(k0, 0, Ah); STAGE_B(k0, 0, Bh);
      STAGE_A(k0, 1, Al); STAGE_B(k0, 1, Bl);
      __syncthreads();
      #pragma unroll
      for (int kk = 0; kk < 2; ++kk) {
        short8v a0[4], b0[4], a1[4], b1[4];
        #pragma unroll
        for (int m = 0; m < 4; ++m) {
          int row = wr + m * 16 + lcol;
          int off = row * 128 + (((kk * 4 + g) ^ (row & 7)) << 4);
          a0[m] = *reinterpret_cast<const short8v*>((const char*)As[0] + off);
          a1[m] = *reinterpret_cast<const short8v*>((const char*)As[1] + off);
        }
        #pragma unroll
        for (int n = 0; n < 4; ++n) {
          int row = wc + n * 16 + lcol;
          int off = row * 128 + (((kk * 4 + g) ^ (row & 7)) << 4);
          b0[n] = *reinterpret_cast<const short8v*>((const char*)Bs[0] + off);
          b1[n] = *reinterpret_cast<const short8v*>((const char*)Bs[1] + off);
        }
        #pragma unroll
        for (int m = 0; m < 4; ++m)
          #pragma unroll
          for (int n = 0; n < 4; ++n) {
            acc[m][n] = __builtin_amdgcn_mfma_f32_16x16x32_bf16(a0[m], b0[n], acc[m][n], 0, 0, 0);
            acc[m][n] = __builtin_amdgcn_mfma_f32_16x16x32_bf16(a0[m], b1[n], acc[m][n], 0, 0, 0);
            acc[m][n] = __builtin_amdgcn_mfma_f32_16x16x32_bf16(a1[m], b0[n], acc[m][n], 0, 0, 0);
          }
      }
    }
  }

  // fused qkv epilogue (mask folded into k)
  const int seg = bn / Cn;
  const int nloc_base = bn - seg * Cn + wc;
  #pragma unroll
  for (int m = 0; m < 4; ++m) {
    const int mg = bm + wr + m * 16 + g * 4;
    const int bidx = mg >> 11;
    const int tbase = mg & (Tn - 1);
    float lgt[4];
    if (seg == 0) {
      #pragma unroll
      for (int j = 0; j < 4; ++j) lgt[j] = logf((float)(tbase + j) + 1.0f);
    }
    float4 mk4;
    if (seg == 1) mk4 = *reinterpret_cast<const float4*>(&attn_mask[bidx * Tn + tbase]);
    const bool wqk = comp ? true : (tbase >= 256);
    #pragma unroll
    for (int n = 0; n < 4; ++n) {
      const int nloc = nloc_base + n * 16 + lcol;
      const int h = nloc >> 6;
      const int d = nloc & 63;
      const size_t bhh = (size_t)(bidx * Hn + h);
      if (seg == 0) {
        if (wqk) {
          const float lam = lambda[h];
          #pragma unroll
          for (int j = 0; j < 4; ++j) {
            float val = acc[m][n][j] * (0.125f * (1.0f + lam * lgt[j]));
            unsigned short hi = f2bf(val);
            size_t idx = (bhh * Tn + tbase + j) * 64 + d;
            qhp[idx] = hi;
            if (comp) qlp[idx] = f2bf(val - bf2f(hi));
          }
        }
      } else if (seg == 1) {
        if (wqk) {
          const float* mkp = &mk4.x;
          #pragma unroll
          for (int j = 0; j < 4; ++j) {
            float val = acc[m][n][j] * mkp[j];
            unsigned short hi = f2bf(val);
            size_t idx = (bhh * Tn + tbase + j) * 64 + d;
            khp[idx] = hi;
            if (comp) klp[idx] = f2bf(val - bf2f(hi));
          }
        }
      } else {
        // blocked v: [bh][kt][64 d][64 t]; 4 j are contiguous t -> one us4
        const int kt_ = tbase >> 6;
        const int tl_ = tbase & 63;
        us4 pv;
        pv.x = f2bf(acc[m][n][0]); pv.y = f2bf(acc[m][n][1]);
        pv.z = f2bf(acc[m][n][2]); pv.w = f2bf(acc[m][n][3]);
        *reinterpret_cast<us4*>(
            &vtp[(((bhh * 32 + kt_) * 64 + d) << 6) + tl_]) = pv;
      }
    }
  }
}

// ---------------- proj GEMM: C = A[M][K] @ Bt[N][K]^T, 64x128, 2-phase ----------
__global__ __launch_bounds__(256) void gemm_proj(
    const ushort_t* __restrict__ Ah, const ushort_t* __restrict__ Bh,
    float* __restrict__ C) {
  constexpr int K = Cn, N = Cn, MT = 64;
  __shared__ ushort_t As[2][MT * 64];
  __shared__ ushort_t Bs[2][128 * 64];

  const int tid = threadIdx.x;
  const int w = tid >> 6;
  const int lane = tid & 63;
  const int lcol = lane & 15;
  const int g = lane >> 4;
  const int id = (blockIdx.x & 7) * (gridDim.x >> 3) + (blockIdx.x >> 3);
  const int bm = (id / 6) * MT;
  const int bn = (id % 6) * 128;
  const int wr = (w >> 1) * 32;
  const int wc = (w & 1) * 64;
  const int srow = tid >> 3;
  const int sslot = tid & 7;

  f32x4 acc[2][4];
  #pragma unroll
  for (int m = 0; m < 2; ++m)
    #pragma unroll
    for (int n = 0; n < 4; ++n)
      acc[m][n] = (f32x4){0.f, 0.f, 0.f, 0.f};

  auto STAGE_A = [&](int k0, int buf) {
    #pragma unroll
    for (int i = 0; i < 2; ++i) {
      const int row = i * 32 + srow;
      const int kslot = sslot ^ (row & 7);
      GLOAD_LDS16(Ah + (size_t)(bm + row) * K + k0 + kslot * 8,
                  (char*)As[buf] + (size_t)(i * 256 + tid) * 16);
    }
  };
  auto STAGE_B = [&](int k0, int buf) {
    #pragma unroll
    for (int i = 0; i < 4; ++i) {
      const int row = i * 32 + srow;
      const int kslot = sslot ^ (row & 7);
      GLOAD_LDS16(Bh + (size_t)(bn + row) * K + k0 + kslot * 8,
                  (char*)Bs[buf] + (size_t)(i * 256 + tid) * 16);
    }
  };

  const int nt = K >> 6;
  STAGE_A(0, 0); STAGE_B(0, 0);
  __syncthreads();
  for (int t = 0; t < nt; ++t) {
    const int cur = t & 1;
    if (t + 1 < nt) { STAGE_A((t + 1) << 6, cur ^ 1); STAGE_B((t + 1) << 6, cur ^ 1); }
    #pragma unroll
    for (int kk = 0; kk < 2; ++kk) {
      short8v a0[2], b0[4];
      #pragma unroll
      for (int m = 0; m < 2; ++m) {
        int row = wr + m * 16 + lcol;
        a0[m] = *reinterpret_cast<const short8v*>(
            (const char*)As[cur] + row * 128 + (((kk * 4 + g) ^ (row & 7)) << 4));
      }
      #pragma unroll
      for (int n = 0; n < 4; ++n) {
        int row = wc + n * 16 + lcol;
        b0[n] = *reinterpret_cast<const short8v*>(
            (const char*)Bs[cur] + row * 128 + (((kk * 4 + g) ^ (row & 7)) << 4));
      }
      #pragma unroll
      for (int m = 0; m < 2; ++m)
        #pragma unroll
        for (int n = 0; n < 4; ++n)
          acc[m][n] = __builtin_amdgcn_mfma_f32_16x16x32_bf16(a0[m], b0[n], acc[m][n], 0, 0, 0);
    }
    __syncthreads();
  }

  #pragma unroll
  for (int m = 0; m < 2; ++m) {
    const int rowm = bm + wr + m * 16 + g * 4;
    #pragma unroll
    for (int n = 0; n < 4; ++n) {
      const int col = bn + wc + n * 16 + lcol;
      #pragma unroll
      for (int j = 0; j < 4; ++j)
        C[(size_t)(rowm + j) * N + col] = acc[m][n][j];
    }
  }
}

// ---------------- MFMA flash-style relu-attention, MERGED paired q-tiles ---------
// pr>=4: qtA=pr and qtB=31-pr share ONE k-loop of length 32-pr (K/V staged once,
// both chains consume the same LDS tiles) -> ~24% fewer stage+barrier steps.
// pr<=3: sequential chains exactly as before (comp path needs Kh_lds[1] for Kl).
// Tiered idx map keeps per-CU step-sums within ~4%; long comp blocks dispatch first.
// Mask pre-folded into k; blocked v; LDS 40 KB; grid 768 = 3 blocks/CU.
__global__ __launch_bounds__(256) void attn_mfma(
    const ushort_t* __restrict__ qh, const ushort_t* __restrict__ ql,
    const ushort_t* __restrict__ kh, const ushort_t* __restrict__ kl,
    const ushort_t* __restrict__ vt, ushort_t* __restrict__ ao) {
  const int xcd = blockIdx.x & 7;
  const int idx = blockIdx.x >> 3;           // 0..95
  const int t_  = idx >> 5;                  // tier 0..2
  const int s_  = idx & 31;
  const int j   = (t_ == 0) ? s_ : (t_ == 1 ? 32 + s_ : 95 - s_);  // bijective
  const int bh  = xcd * 6 + (j % 6);         // 0..47
  const int pr  = j / 6;                     // 0..15
  const int b = bh / Hn, h = bh % Hn;
  const int tid = threadIdx.x;
  const int w = tid >> 6, lane = tid & 63, lcol = lane & 15, g = lane >> 4;

  __shared__ ushort_t Kh_lds[2][64 * 64];   // 16 KB (buf 1 doubles as Kl for qt<=1)
  __shared__ ushort_t V_lds[2][64 * 64];    // 16 KB
  __shared__ ushort_t P_lds[4][16 * 64];    // 8 KB, per-wave [16 q][64 k], XOR-swz

  char* pb = (char*)P_lds[w];
  const int pswz = (lcol & 7) << 4;

  auto STAGE = [&](int kt, int d) {
    const ushort_t* ks = kh + ((size_t)bh * Tn + kt * 64) * 64;
    const ushort_t* vs = vt + ((size_t)bh * 32 + kt) * 64 * 64;   // blocked tile
    #pragma unroll
    for (int it = 0; it < 2; ++it) {
      const int s = it * 256 + tid;
      const int row = s >> 3, sslot = s & 7;
      const int swz = (sslot ^ (row & 7)) * 8;
      GLOAD_LDS16(ks + row * 64 + swz, (char*)Kh_lds[d] + (size_t)s * 16);
      GLOAD_LDS16(vs + row * 64 + swz, (char*)V_lds[d] + (size_t)s * 16);
    }
  };
  auto STAGE_KL = [&](int kt) {   // qt<=1 only: Kl parked in Kh_lds[1]
    const ushort_t* ls = kl + ((size_t)bh * Tn + kt * 64) * 64;
    #pragma unroll
    for (int it = 0; it < 2; ++it) {
      const int s = it * 256 + tid;
      const int row = s >> 3, sslot = s & 7;
      const int swz = (sslot ^ (row & 7)) * 8;
      GLOAD_LDS16(ls + row * 64 + swz, (char*)Kh_lds[1] + (size_t)s * 16);
    }
  };

  // one k-tile of QK^T + PV for q-tile qt_ into (o_, ds_)
  auto QKPV = [&](int kt, int d, int qt_, size_t qoff_, short8v qf0, short8v qf1,
                  bool cq, bool ck, f32x4 (&o_)[4], float& ds_) {
    const bool diag = (kt == qt_);
    const int qr = qt_ * 64 + w * 16 + lcol;
    short8v qfl0, qfl1;
    if (cq) {
      qfl0 = *reinterpret_cast<const short8v*>(ql + qoff_ + g * 8);
      qfl1 = *reinterpret_cast<const short8v*>(ql + qoff_ + 32 + g * 8);
    }
    #pragma unroll
    for (int c = 0; c < 4; ++c) {
      const int row = c * 16 + lcol;
      const int roff = row * 128;
      const int s0 = (g ^ (row & 7)) << 4;
      const int s1 = ((4 + g) ^ (row & 7)) << 4;
      short8v kf0 = *reinterpret_cast<const short8v*>((const char*)Kh_lds[d] + roff + s0);
      short8v kf1 = *reinterpret_cast<const short8v*>((const char*)Kh_lds[d] + roff + s1);
      f32x4 s = (f32x4){0.f, 0.f, 0.f, 0.f};
      __builtin_amdgcn_s_setprio(1);
      s = __builtin_amdgcn_mfma_f32_16x16x32_bf16(kf0, qf0, s, 0, 0, 0);
      s = __builtin_amdgcn_mfma_f32_16x16x32_bf16(kf1, qf1, s, 0, 0, 0);
      if (cq) {
        s = __builtin_amdgcn_mfma_f32_16x16x32_bf16(kf0, qfl0, s, 0, 0, 0);
        s = __builtin_amdgcn_mfma_f32_16x16x32_bf16(kf1, qfl1, s, 0, 0, 0);
      }
      if (ck) {
        short8v kl0 = *reinterpret_cast<const short8v*>((const char*)Kh_lds[1] + roff + s0);
        short8v kl1 = *reinterpret_cast<const short8v*>((const char*)Kh_lds[1] + roff + s1);
        s = __builtin_amdgcn_mfma_f32_16x16x32_bf16(kl0, qf0, s, 0, 0, 0);
        s = __builtin_amdgcn_mfma_f32_16x16x32_bf16(kl1, qf1, s, 0, 0, 0);
      }
      __builtin_amdgcn_s_setprio(0);
      // lane holds S^T[k = kt*64 + c*16 + g*4 + r][q = qr]; mask already in k.
      float sv[4];
      if (diag) {
        #pragma unroll
        for (int r = 0; r < 4; ++r) {
          float v = fmaxf(s[r], 0.f);
          const int kr = kt * 64 + c * 16 + g * 4 + r;
          sv[r] = (kr <= qr) ? v : 0.f;
        }
      } else {
        #pragma unroll
        for (int r = 0; r < 4; ++r) sv[r] = fmaxf(s[r], 0.f);
      }
      const unsigned p01 = cvt_pk_bf16(sv[0], sv[1]);
      const unsigned p23 = cvt_pk_bf16(sv[2], sv[3]);
      *reinterpret_cast<uint2*>(pb + lcol * 128 + ((c * 32 + g * 8) ^ pswz)) =
          make_uint2(p01, p23);
      ds_ += (sv[0] + sv[1]) + (sv[2] + sv[3]);
    }
    // PV (same-wave LDS ordering; P region is wave-private)
    short8v pf0 = *reinterpret_cast<const short8v*>(pb + lcol * 128 + ((g * 16) ^ pswz));
    short8v pf1 = *reinterpret_cast<const short8v*>(pb + lcol * 128 + ((64 + g * 16) ^ pswz));
    __builtin_amdgcn_s_setprio(1);
    #pragma unroll
    for (int dt = 0; dt < 4; ++dt) {
      const int vrow = dt * 16 + lcol;
      const int vro = vrow * 128;
      short8v vf0 = *reinterpret_cast<const short8v*>(
          (const char*)V_lds[d] + vro + ((g ^ (vrow & 7)) << 4));
      short8v vf1 = *reinterpret_cast<const short8v*>(
          (const char*)V_lds[d] + vro + (((4 + g) ^ (vrow & 7)) << 4));
      o_[dt] = __builtin_amdgcn_mfma_f32_16x16x32_bf16(pf0, vf0, o_[dt], 0, 0, 0);
      o_[dt] = __builtin_amdgcn_mfma_f32_16x16x32_bf16(pf1, vf1, o_[dt], 0, 0, 0);
    }
    __builtin_amdgcn_s_setprio(0);
  };

  auto WRITEOUT = [&](int qt_, f32x4 (&o_)[4], float ds_) {
    float dtot = ds_;
    dtot += __shfl_xor(dtot, 16);
    dtot += __shfl_xor(dtot, 32);
    const float invq = 1.0f / (dtot + 1e-9f);
    float invs[4];
    #pragma unroll
    for (int r = 0; r < 4; ++r) invs[r] = __shfl(invq, g * 4 + r);
    ushort_t* ob = ao + ((size_t)b * Tn + qt_ * 64 + w * 16) * Cn + h * 64;
    #pragma unroll
    for (int dt = 0; dt < 4; ++dt)
      #pragma unroll
      for (int r = 0; r < 4; ++r)
        ob[(size_t)(g * 4 + r) * Cn + dt * 16 + lcol] = f2bf(o_[dt][r] * invs[r]);
  };

  if (pr <= 3) {
    // sequential chains (comp path); identical to proven round-24 behavior
    for (int segq = 0; segq < 2; ++segq) {
      const int qt = segq ? (31 - pr) : pr;
      const bool compq = (qt <= 3);
      const size_t qoff0 = ((size_t)bh * Tn + qt * 64 + w * 16 + lcol) * 64;
      short8v qfh0 = *reinterpret_cast<const short8v*>(qh + qoff0 + g * 8);
      short8v qfh1 = *reinterpret_cast<const short8v*>(qh + qoff0 + 32 + g * 8);
      f32x4 o[4];
      #pragma unroll
      for (int dt = 0; dt < 4; ++dt) o[dt] = (f32x4){0.f, 0.f, 0.f, 0.f};
      float dsum = 0.f;
      if (qt <= 1) {
        for (int kt = 0; kt <= qt; ++kt) {
          STAGE(kt, 0);
          STAGE_KL(kt);
          __syncthreads();
          QKPV(kt, 0, qt, qoff0, qfh0, qfh1, true, true, o, dsum);
          __syncthreads();
        }
      } else {
        const int ntiles = qt + 1;
        STAGE(0, 0);
        __syncthreads();
        for (int kt = 0; kt < ntiles; ++kt) {
          const int d = kt & 1;
          if (kt + 1 < ntiles) STAGE(kt + 1, d ^ 1);
          QKPV(kt, d, qt, qoff0, qfh0, qfh1, compq, false, o, dsum);
          __syncthreads();
        }
      }
      WRITEOUT(qt, o, dsum);
    }
  } else {
    // MERGED: both chains plain, one k-loop of length 32-pr
    const int qtA = pr, qtB = 31 - pr;
    const size_t qoffA = ((size_t)bh * Tn + qtA * 64 + w * 16 + lcol) * 64;
    const size_t qoffB = ((size_t)bh * Tn + qtB * 64 + w * 16 + lcol) * 64;
    short8v qfA0 = *reinterpret_cast<const short8v*>(qh + qoffA + g * 8);
    short8v qfA1 = *reinterpret_cast<const short8v*>(qh + qoffA + 32 + g * 8);
    short8v qfB0 = *reinterpret_cast<const short8v*>(qh + qoffB + g * 8);
    short8v qfB1 = *reinterpret_cast<const short8v*>(qh + qoffB + 32 + g * 8);
    f32x4 oA[4], oB[4];
    #pragma unroll
    for (int dt = 0; dt < 4; ++dt) {
      oA[dt] = (f32x4){0.f, 0.f, 0.f, 0.f};
      oB[dt] = (f32x4){0.f, 0.f, 0.f, 0.f};
    }
    float dsA = 0.f, dsB = 0.f;
    const int nt_ = qtB + 1;               // 32-pr >= 17
    STAGE(0, 0);
    __syncthreads();
    for (int kt = 0; kt < nt_; ++kt) {
      const int d = kt & 1;
      if (kt + 1 < nt_) STAGE(kt + 1, d ^ 1);
      QKPV(kt, d, qtB, qoffB, qfB0, qfB1, false, false, oB, dsB);
      if (kt <= qtA)
        QKPV(kt, d, qtA, qoffA, qfA0, qfA1, false, false, oA, dsA);
      __syncthreads();
    }
    WRITEOUT(qtA, oA, dsA);
    WRITEOUT(qtB, oB, dsB);
  }
}

extern "C" void kernel_launch(void* const* d_in, const int* in_sizes, int n_in,
                              void* d_out, int out_size, void* d_ws, size_t ws_size,
                              hipStream_t stream) {
  const float* x         = (const float*)d_in[0];
  const float* attn_mask = (const float*)d_in[1];
  const float* lambda    = (const float*)d_in[2];
  const float* W_attn    = (const float*)d_in[3];
  const float* W_proj    = (const float*)d_in[4];
  float* out = (float*)d_out;

  const size_t nBTC = (size_t)Bn * Tn * Cn;        // 6.29M
  const size_t nW1  = (size_t)Cn * 3 * Cn;         // 1.77M
  const size_t nW2  = (size_t)Cn * Cn;             // 0.59M
  ushort_t* xh  = (ushort_t*)d_ws;
  ushort_t* xl  = xh + nBTC;
  ushort_t* WhT = xl + nBTC;
  ushort_t* WlT = WhT + nW1;
  ushort_t* WpT = WlT + nW1;
  ushort_t* qh  = WpT + nW2;
  ushort_t* ql  = qh + nBTC;
  ushort_t* kh  = ql + nBTC;
  ushort_t* kl  = kh + nBTC;
  ushort_t* vt  = kl + nBTC;
  ushort_t* ao  = xh;   // xh dead after qkv GEMM; reuse for attention output

  dim3 blk(256);

  prep_all<<<dim3(6720), blk, 0, stream>>>(
      x, xh, xl, W_attn, WhT, WlT, W_proj, WpT);

  gemm_qkv_fused<<<dim3(1248), blk, 0, stream>>>(
      xh, xl, WhT, WlT, lambda, attn_mask, qh, ql, kh, kl, vt);

  attn_mfma<<<dim3(768), blk, 0, stream>>>(
      qh, ql, kh, kl, vt, ao);

  gemm_proj<<<dim3(768), blk, 0, stream>>>(ao, WpT, out);
}

// Round 28
// 128.500 us; speedup vs baseline: 1.1152x; 1.1152x over previous
//
#include <hip/hip_runtime.h>
#include <cstddef>
#include <cstdint>

#define Bn 4
#define Tn 2048
#define Cn 768
#define Hn 12

typedef __attribute__((ext_vector_type(8))) short short8v;
typedef __attribute__((ext_vector_type(4))) float f32x4;
typedef unsigned short ushort_t;

struct us4 { unsigned short x, y, z, w; };

__device__ inline unsigned short f2bf(float f) {
  union { float f; unsigned u; } v; v.f = f;
  unsigned r = v.u + 0x7FFFu + ((v.u >> 16) & 1u);
  return (unsigned short)(r >> 16);
}
__device__ inline float bf2f(unsigned short u) {
  union { unsigned u; float f; } v; v.u = ((unsigned)u) << 16;
  return v.f;
}
__device__ inline unsigned cvt_pk_bf16(float lo, float hi) {
  unsigned r;
  asm("v_cvt_pk_bf16_f32 %0, %1, %2" : "=v"(r) : "v"(lo), "v"(hi));
  return r;
}

#define GLOAD_LDS16(gp, lp)                                                        \
  __builtin_amdgcn_global_load_lds(                                                \
      (const __attribute__((address_space(1))) void*)(gp),                         \
      (__attribute__((address_space(3))) void*)(lp), 16, 0, 0)

// -------- ONE prep launch: blocks 0..6143 -> x split; 6144..6719 -> W transposes --
__global__ __launch_bounds__(256) void prep_all(
    const float* __restrict__ x, ushort_t* __restrict__ xh, ushort_t* __restrict__ xl,
    const float* __restrict__ Wa, ushort_t* __restrict__ WaTh,
    ushort_t* __restrict__ WaTl, const float* __restrict__ Wp,
    ushort_t* __restrict__ WpT) {
  __shared__ float t[64][65];
  const int blk = blockIdx.x;
  const int tid = threadIdx.x;
  if (blk < 6144) {
    const int i = blk * 256 + tid;
    float4 v = reinterpret_cast<const float4*>(x)[i];
    us4 h;
    h.x = f2bf(v.x); h.y = f2bf(v.y); h.z = f2bf(v.z); h.w = f2bf(v.w);
    reinterpret_cast<us4*>(xh)[i] = h;
    const int row = (i << 2) / Cn;
    if ((row & (Tn - 1)) < 256) {
      us4 l;
      l.x = f2bf(v.x - bf2f(h.x)); l.y = f2bf(v.y - bf2f(h.y));
      l.z = f2bf(v.z - bf2f(h.z)); l.w = f2bf(v.w - bf2f(h.w));
      reinterpret_cast<us4*>(xl)[i] = l;
    }
    return;
  }
  const int id2 = blk - 6144;           // 0..575
  const int cx  = id2 % 48;             // 0..47
  const int ry  = id2 / 48;             // 0..11
  const bool split = (cx < 36);
  const float* W = split ? Wa : Wp;
  ushort_t* WTh  = split ? WaTh : WpT;
  const int cols = split ? 3 * Cn : Cn;
  const int c0   = (split ? cx : (cx - 36)) * 64;
  const int r0   = ry * 64;
  const int rows = Cn;
  const int c4 = (tid & 15) << 2;
  #pragma unroll
  for (int rr = 0; rr < 4; ++rr) {
    int r = rr * 16 + (tid >> 4);
    float4 v = *reinterpret_cast<const float4*>(&W[(size_t)(r0 + r) * cols + c0 + c4]);
    t[r][c4] = v.x; t[r][c4 + 1] = v.y; t[r][c4 + 2] = v.z; t[r][c4 + 3] = v.w;
  }
  __syncthreads();
  const int r4 = (tid & 15) << 2;
  #pragma unroll
  for (int cc = 0; cc < 4; ++cc) {
    int c = cc * 16 + (tid >> 4);
    float v0 = t[r4][c], v1 = t[r4 + 1][c], v2 = t[r4 + 2][c], v3 = t[r4 + 3][c];
    us4 h;
    h.x = f2bf(v0); h.y = f2bf(v1); h.z = f2bf(v2); h.w = f2bf(v3);
    *reinterpret_cast<us4*>(&WTh[(size_t)(c0 + c) * rows + r0 + r4]) = h;
    if (split) {
      us4 l;
      l.x = f2bf(v0 - bf2f(h.x)); l.y = f2bf(v1 - bf2f(h.y));
      l.z = f2bf(v2 - bf2f(h.z)); l.w = f2bf(v3 - bf2f(h.w));
      *reinterpret_cast<us4*>(&WaTl[(size_t)(c0 + c) * rows + r0 + r4]) = l;
    }
  }
}

// -------- FUSED qkv GEMM, XCD-BALANCED (12 comp blocks first + 144 plain per XCD).
//          attn_mask FOLDED INTO k (valid since mask>=0: relu(m*s)=m*relu(s)) -----
__global__ __launch_bounds__(256) void gemm_qkv_fused(
    const ushort_t* __restrict__ Ah, const ushort_t* __restrict__ Al,
    const ushort_t* __restrict__ Bh, const ushort_t* __restrict__ Bl,
    const float* __restrict__ lambda, const float* __restrict__ attn_mask,
    ushort_t* __restrict__ qhp, ushort_t* __restrict__ qlp,
    ushort_t* __restrict__ khp, ushort_t* __restrict__ klp,
    ushort_t* __restrict__ vtp) {
  constexpr int K = Cn, N = 3 * Cn;
  __shared__ ushort_t As[2][128 * 64];
  __shared__ ushort_t Bs[2][128 * 64];

  const int tid = threadIdx.x;
  const int w = tid >> 6;
  const int lane = tid & 63;
  const int lcol = lane & 15;
  const int g = lane >> 4;
  const int xcd = blockIdx.x & 7;
  const int pos = blockIdx.x >> 3;          // 0..155
  const bool comp = (pos < 12);
  int bm, bn;
  if (comp) {
    const int cid = xcd * 12 + pos;         // 0..95; byi == xcd
    bm = (xcd >> 1) * Tn + (xcd & 1) * 128;
    bn = (cid % 12) * 128;
  } else {
    const int pid = xcd * 144 + (pos - 12); // 0..1151
    bm = (pid / 18) * 128;
    bn = (pid % 18) * 128;
  }
  const int wr = (w >> 1) * 64;
  const int wc = (w & 1) * 64;
  const int srow = tid >> 3;
  const int sslot = tid & 7;

  f32x4 acc[4][4];
  #pragma unroll
  for (int m = 0; m < 4; ++m)
    #pragma unroll
    for (int n = 0; n < 4; ++n)
      acc[m][n] = (f32x4){0.f, 0.f, 0.f, 0.f};

  auto STAGE_A = [&](int k0, int buf, const ushort_t* A) {
    #pragma unroll
    for (int i = 0; i < 4; ++i) {
      const int row = i * 32 + srow;
      const int kslot = sslot ^ (row & 7);
      GLOAD_LDS16(A + (size_t)(bm + row) * K + k0 + kslot * 8,
                  (char*)As[buf] + (size_t)(i * 256 + tid) * 16);
    }
  };
  auto STAGE_B = [&](int k0, int buf, const ushort_t* B) {
    #pragma unroll
    for (int i = 0; i < 4; ++i) {
      const int row = i * 32 + srow;
      const int kslot = sslot ^ (row & 7);
      GLOAD_LDS16(B + (size_t)(bn + row) * K + k0 + kslot * 8,
                  (char*)Bs[buf] + (size_t)(i * 256 + tid) * 16);
    }
  };

  const int nt = K >> 6;
  if (!comp) {
    STAGE_A(0, 0, Ah); STAGE_B(0, 0, Bh);
    __syncthreads();
    for (int t = 0; t < nt; ++t) {
      const int cur = t & 1;
      if (t + 1 < nt) { STAGE_A((t + 1) << 6, cur ^ 1, Ah); STAGE_B((t + 1) << 6, cur ^ 1, Bh); }
      #pragma unroll
      for (int kk = 0; kk < 2; ++kk) {
        short8v a0[4], b0[4];
        #pragma unroll
        for (int m = 0; m < 4; ++m) {
          int row = wr + m * 16 + lcol;
          a0[m] = *reinterpret_cast<const short8v*>(
              (const char*)As[cur] + row * 128 + (((kk * 4 + g) ^ (row & 7)) << 4));
        }
        #pragma unroll
        for (int n = 0; n < 4; ++n) {
          int row = wc + n * 16 + lcol;
          b0[n] = *reinterpret_cast<const short8v*>(
              (const char*)Bs[cur] + row * 128 + (((kk * 4 + g) ^ (row & 7)) << 4));
        }
        #pragma unroll
        for (int m = 0; m < 4; ++m)
          #pragma unroll
          for (int n = 0; n < 4; ++n)
            acc[m][n] = __builtin_amdgcn_mfma_f32_16x16x32_bf16(a0[m], b0[n], acc[m][n], 0, 0, 0);
      }
      __syncthreads();
    }
  } else {
    for (int t = 0; t < nt; ++t) {
      const int k0 = t << 6;
      __syncthreads();
      STAGE_A(k0, 0, Ah); STAGE_B(k0, 0, Bh);
      STAGE_A(k0, 1, Al); STAGE_B(k0, 1, Bl);
      __syncthreads();
      #pragma unroll
      for (int kk = 0; kk < 2; ++kk) {
        short8v a0[4], b0[4], a1[4], b1[4];
        #pragma unroll
        for (int m = 0; m < 4; ++m) {
          int row = wr + m * 16 + lcol;
          int off = row * 128 + (((kk * 4 + g) ^ (row & 7)) << 4);
          a0[m] = *reinterpret_cast<const short8v*>((const char*)As[0] + off);
          a1[m] = *reinterpret_cast<const short8v*>((const char*)As[1] + off);
        }
        #pragma unroll
        for (int n = 0; n < 4; ++n) {
          int row = wc + n * 16 + lcol;
          int off = row * 128 + (((kk * 4 + g) ^ (row & 7)) << 4);
          b0[n] = *reinterpret_cast<const short8v*>((const char*)Bs[0] + off);
          b1[n] = *reinterpret_cast<const short8v*>((const char*)Bs[1] + off);
        }
        #pragma unroll
        for (int m = 0; m < 4; ++m)
          #pragma unroll
          for (int n = 0; n < 4; ++n) {
            acc[m][n] = __builtin_amdgcn_mfma_f32_16x16x32_bf16(a0[m], b0[n], acc[m][n], 0, 0, 0);
            acc[m][n] = __builtin_amdgcn_mfma_f32_16x16x32_bf16(a0[m], b1[n], acc[m][n], 0, 0, 0);
            acc[m][n] = __builtin_amdgcn_mfma_f32_16x16x32_bf16(a1[m], b0[n], acc[m][n], 0, 0, 0);
          }
      }
    }
  }

  // fused qkv epilogue (mask folded into k)
  const int seg = bn / Cn;
  const int nloc_base = bn - seg * Cn + wc;
  #pragma unroll
  for (int m = 0; m < 4; ++m) {
    const int mg = bm + wr + m * 16 + g * 4;
    const int bidx = mg >> 11;
    const int tbase = mg & (Tn - 1);
    float lgt[4];
    if (seg == 0) {
      #pragma unroll
      for (int j = 0; j < 4; ++j) lgt[j] = logf((float)(tbase + j) + 1.0f);
    }
    float4 mk4;
    if (seg == 1) mk4 = *reinterpret_cast<const float4*>(&attn_mask[bidx * Tn + tbase]);
    const bool wqk = comp ? true : (tbase >= 256);
    #pragma unroll
    for (int n = 0; n < 4; ++n) {
      const int nloc = nloc_base + n * 16 + lcol;
      const int h = nloc >> 6;
      const int d = nloc & 63;
      const size_t bhh = (size_t)(bidx * Hn + h);
      if (seg == 0) {
        if (wqk) {
          const float lam = lambda[h];
          #pragma unroll
          for (int j = 0; j < 4; ++j) {
            float val = acc[m][n][j] * (0.125f * (1.0f + lam * lgt[j]));
            unsigned short hi = f2bf(val);
            size_t idx = (bhh * Tn + tbase + j) * 64 + d;
            qhp[idx] = hi;
            if (comp) qlp[idx] = f2bf(val - bf2f(hi));
          }
        }
      } else if (seg == 1) {
        if (wqk) {
          const float* mkp = &mk4.x;
          #pragma unroll
          for (int j = 0; j < 4; ++j) {
            float val = acc[m][n][j] * mkp[j];
            unsigned short hi = f2bf(val);
            size_t idx = (bhh * Tn + tbase + j) * 64 + d;
            khp[idx] = hi;
            if (comp) klp[idx] = f2bf(val - bf2f(hi));
          }
        }
      } else {
        // blocked v: [bh][kt][64 d][64 t]; 4 j are contiguous t -> one us4
        const int kt_ = tbase >> 6;
        const int tl_ = tbase & 63;
        us4 pv;
        pv.x = f2bf(acc[m][n][0]); pv.y = f2bf(acc[m][n][1]);
        pv.z = f2bf(acc[m][n][2]); pv.w = f2bf(acc[m][n][3]);
        *reinterpret_cast<us4*>(
            &vtp[(((bhh * 32 + kt_) * 64 + d) << 6) + tl_]) = pv;
      }
    }
  }
}

// ---------------- proj GEMM: C = A[M][K] @ Bt[N][K]^T, 64x128, 2-phase ----------
__global__ __launch_bounds__(256) void gemm_proj(
    const ushort_t* __restrict__ Ah, const ushort_t* __restrict__ Bh,
    float* __restrict__ C) {
  constexpr int K = Cn, N = Cn, MT = 64;
  __shared__ ushort_t As[2][MT * 64];
  __shared__ ushort_t Bs[2][128 * 64];

  const int tid = threadIdx.x;
  const int w = tid >> 6;
  const int lane = tid & 63;
  const int lcol = lane & 15;
  const int g = lane >> 4;
  const int id = (blockIdx.x & 7) * (gridDim.x >> 3) + (blockIdx.x >> 3);
  const int bm = (id / 6) * MT;
  const int bn = (id % 6) * 128;
  const int wr = (w >> 1) * 32;
  const int wc = (w & 1) * 64;
  const int srow = tid >> 3;
  const int sslot = tid & 7;

  f32x4 acc[2][4];
  #pragma unroll
  for (int m = 0; m < 2; ++m)
    #pragma unroll
    for (int n = 0; n < 4; ++n)
      acc[m][n] = (f32x4){0.f, 0.f, 0.f, 0.f};

  auto STAGE_A = [&](int k0, int buf) {
    #pragma unroll
    for (int i = 0; i < 2; ++i) {
      const int row = i * 32 + srow;
      const int kslot = sslot ^ (row & 7);
      GLOAD_LDS16(Ah + (size_t)(bm + row) * K + k0 + kslot * 8,
                  (char*)As[buf] + (size_t)(i * 256 + tid) * 16);
    }
  };
  auto STAGE_B = [&](int k0, int buf) {
    #pragma unroll
    for (int i = 0; i < 4; ++i) {
      const int row = i * 32 + srow;
      const int kslot = sslot ^ (row & 7);
      GLOAD_LDS16(Bh + (size_t)(bn + row) * K + k0 + kslot * 8,
                  (char*)Bs[buf] + (size_t)(i * 256 + tid) * 16);
    }
  };

  const int nt = K >> 6;
  STAGE_A(0, 0); STAGE_B(0, 0);
  __syncthreads();
  for (int t = 0; t < nt; ++t) {
    const int cur = t & 1;
    if (t + 1 < nt) { STAGE_A((t + 1) << 6, cur ^ 1); STAGE_B((t + 1) << 6, cur ^ 1); }
    #pragma unroll
    for (int kk = 0; kk < 2; ++kk) {
      short8v a0[2], b0[4];
      #pragma unroll
      for (int m = 0; m < 2; ++m) {
        int row = wr + m * 16 + lcol;
        a0[m] = *reinterpret_cast<const short8v*>(
            (const char*)As[cur] + row * 128 + (((kk * 4 + g) ^ (row & 7)) << 4));
      }
      #pragma unroll
      for (int n = 0; n < 4; ++n) {
        int row = wc + n * 16 + lcol;
        b0[n] = *reinterpret_cast<const short8v*>(
            (const char*)Bs[cur] + row * 128 + (((kk * 4 + g) ^ (row & 7)) << 4));
      }
      #pragma unroll
      for (int m = 0; m < 2; ++m)
        #pragma unroll
        for (int n = 0; n < 4; ++n)
          acc[m][n] = __builtin_amdgcn_mfma_f32_16x16x32_bf16(a0[m], b0[n], acc[m][n], 0, 0, 0);
    }
    __syncthreads();
  }

  #pragma unroll
  for (int m = 0; m < 2; ++m) {
    const int rowm = bm + wr + m * 16 + g * 4;
    #pragma unroll
    for (int n = 0; n < 4; ++n) {
      const int col = bn + wc + n * 16 + lcol;
      #pragma unroll
      for (int j = 0; j < 4; ++j)
        C[(size_t)(rowm + j) * N + col] = acc[m][n][j];
    }
  }
}

// ---------------- MFMA flash-style relu-attention, PAIRED q-tiles ----------------
// Mask pre-folded into k (qkv epilogue) -> inner loop is mask-free.
// Each block runs qt=pr then qt=31-pr -> EXACTLY 33 k-tiles per block.
// Grid 768 = 48 bh x 16 pairs = 3 blocks/CU; XCD-aware bh binding; LDS 40 KB.
__global__ __launch_bounds__(256) void attn_mfma(
    const ushort_t* __restrict__ qh, const ushort_t* __restrict__ ql,
    const ushort_t* __restrict__ kh, const ushort_t* __restrict__ kl,
    const ushort_t* __restrict__ vt, ushort_t* __restrict__ ao) {
  const int xcd = blockIdx.x & 7;
  const int idx = blockIdx.x >> 3;           // 0..95
  const int bh  = xcd * 6 + (idx % 6);       // 0..47
  const int pr  = idx / 6;                   // 0..15
  const int b = bh / Hn, h = bh % Hn;
  const int tid = threadIdx.x;
  const int w = tid >> 6, lane = tid & 63, lcol = lane & 15, g = lane >> 4;

  __shared__ ushort_t Kh_lds[2][64 * 64];   // 16 KB (buf 1 doubles as Kl for qt<=1)
  __shared__ ushort_t V_lds[2][64 * 64];    // 16 KB
  __shared__ ushort_t P_lds[4][16 * 64];    // 8 KB, per-wave [16 q][64 k], XOR-swz

  for (int segq = 0; segq < 2; ++segq) {
    const int qt = segq ? (31 - pr) : pr;
    const bool compq = (qt <= 3);

    const size_t qoff0 = ((size_t)bh * Tn + qt * 64 + w * 16 + lcol) * 64;
    short8v qfh0 = *reinterpret_cast<const short8v*>(qh + qoff0 + g * 8);
    short8v qfh1 = *reinterpret_cast<const short8v*>(qh + qoff0 + 32 + g * 8);

    f32x4 o[4];
    #pragma unroll
    for (int dt = 0; dt < 4; ++dt) o[dt] = (f32x4){0.f, 0.f, 0.f, 0.f};
    float dsum = 0.f;

    auto STAGE = [&](int kt, int d) {
      const ushort_t* ks = kh + ((size_t)bh * Tn + kt * 64) * 64;
      const ushort_t* vs = vt + ((size_t)bh * 32 + kt) * 64 * 64;   // blocked tile
      #pragma unroll
      for (int it = 0; it < 2; ++it) {
        const int s = it * 256 + tid;
        const int row = s >> 3, sslot = s & 7;
        const int swz = (sslot ^ (row & 7)) * 8;
        GLOAD_LDS16(ks + row * 64 + swz, (char*)Kh_lds[d] + (size_t)s * 16);
        GLOAD_LDS16(vs + row * 64 + swz, (char*)V_lds[d] + (size_t)s * 16);
      }
    };
    auto STAGE_KL = [&](int kt) {   // qt<=1 only: Kl parked in Kh_lds[1]
      const ushort_t* ls = kl + ((size_t)bh * Tn + kt * 64) * 64;
      #pragma unroll
      for (int it = 0; it < 2; ++it) {
        const int s = it * 256 + tid;
        const int row = s >> 3, sslot = s & 7;
        const int swz = (sslot ^ (row & 7)) * 8;
        GLOAD_LDS16(ls + row * 64 + swz, (char*)Kh_lds[1] + (size_t)s * 16);
      }
    };

    auto COMPUTE = [&](int kt, int d, bool cq, bool ck) {
      const bool diag = (kt == qt);
      const int qr = qt * 64 + w * 16 + lcol;
      short8v qfl0, qfl1;
      if (cq) {
        qfl0 = *reinterpret_cast<const short8v*>(ql + qoff0 + g * 8);
        qfl1 = *reinterpret_cast<const short8v*>(ql + qoff0 + 32 + g * 8);
      }
      char* pb = (char*)P_lds[w];
      const int pswz = (lcol & 7) << 4;
      #pragma unroll
      for (int c = 0; c < 4; ++c) {
        const int row = c * 16 + lcol;
        const int roff = row * 128;
        const int s0 = (g ^ (row & 7)) << 4;
        const int s1 = ((4 + g) ^ (row & 7)) << 4;
        short8v kf0 = *reinterpret_cast<const short8v*>((const char*)Kh_lds[d] + roff + s0);
        short8v kf1 = *reinterpret_cast<const short8v*>((const char*)Kh_lds[d] + roff + s1);
        f32x4 s = (f32x4){0.f, 0.f, 0.f, 0.f};
        __builtin_amdgcn_s_setprio(1);
        s = __builtin_amdgcn_mfma_f32_16x16x32_bf16(kf0, qfh0, s, 0, 0, 0);
        s = __builtin_amdgcn_mfma_f32_16x16x32_bf16(kf1, qfh1, s, 0, 0, 0);
        if (cq) {
          s = __builtin_amdgcn_mfma_f32_16x16x32_bf16(kf0, qfl0, s, 0, 0, 0);
          s = __builtin_amdgcn_mfma_f32_16x16x32_bf16(kf1, qfl1, s, 0, 0, 0);
        }
        if (ck) {
          short8v kl0 = *reinterpret_cast<const short8v*>((const char*)Kh_lds[1] + roff + s0);
          short8v kl1 = *reinterpret_cast<const short8v*>((const char*)Kh_lds[1] + roff + s1);
          s = __builtin_amdgcn_mfma_f32_16x16x32_bf16(kl0, qfh0, s, 0, 0, 0);
          s = __builtin_amdgcn_mfma_f32_16x16x32_bf16(kl1, qfh1, s, 0, 0, 0);
        }
        __builtin_amdgcn_s_setprio(0);
        // lane holds S^T[k = kt*64 + c*16 + g*4 + r][q = qr]; mask already in k.
        float sv[4];
        if (diag) {                         // uniform branch: 2/33 tiles only
          #pragma unroll
          for (int r = 0; r < 4; ++r) {
            float v = fmaxf(s[r], 0.f);
            const int kr = kt * 64 + c * 16 + g * 4 + r;
            sv[r] = (kr <= qr) ? v : 0.f;
          }
        } else {
          #pragma unroll
          for (int r = 0; r < 4; ++r) sv[r] = fmaxf(s[r], 0.f);
        }
        const unsigned p01 = cvt_pk_bf16(sv[0], sv[1]);
        const unsigned p23 = cvt_pk_bf16(sv[2], sv[3]);
        *reinterpret_cast<uint2*>(pb + lcol * 128 + ((c * 32 + g * 8) ^ pswz)) =
            make_uint2(p01, p23);
        dsum += (sv[0] + sv[1]) + (sv[2] + sv[3]);
      }
      // PV (same-wave LDS ordering; P region is wave-private)
      short8v pf0 = *reinterpret_cast<const short8v*>(pb + lcol * 128 + ((g * 16) ^ pswz));
      short8v pf1 = *reinterpret_cast<const short8v*>(pb + lcol * 128 + ((64 + g * 16) ^ pswz));
      __builtin_amdgcn_s_setprio(1);
      #pragma unroll
      for (int dt = 0; dt < 4; ++dt) {
        const int vrow = dt * 16 + lcol;
        const int vro = vrow * 128;
        short8v vf0 = *reinterpret_cast<const short8v*>(
            (const char*)V_lds[d] + vro + ((g ^ (vrow & 7)) << 4));
        short8v vf1 = *reinterpret_cast<const short8v*>(
            (const char*)V_lds[d] + vro + (((4 + g) ^ (vrow & 7)) << 4));
        o[dt] = __builtin_amdgcn_mfma_f32_16x16x32_bf16(pf0, vf0, o[dt], 0, 0, 0);
        o[dt] = __builtin_amdgcn_mfma_f32_16x16x32_bf16(pf1, vf1, o[dt], 0, 0, 0);
      }
      __builtin_amdgcn_s_setprio(0);
    };

    if (qt <= 1) {
      // <=2 tiles, sequential, full q+k compensation (knife-edge rows t<128)
      for (int kt = 0; kt <= qt; ++kt) {
        STAGE(kt, 0);
        STAGE_KL(kt);
        __syncthreads();
        COMPUTE(kt, 0, true, true);
        __syncthreads();
      }
    } else {
      const int ntiles = qt + 1;
      STAGE(0, 0);
      __syncthreads();
      for (int kt = 0; kt < ntiles; ++kt) {
        const int d = kt & 1;
        if (kt + 1 < ntiles) STAGE(kt + 1, d ^ 1);
        COMPUTE(kt, d, compq, false);
        __syncthreads();
      }
    }

    // dsum holds partial den for q=lcol (this lane's k-slices); reduce over g.
    float dtot = dsum;
    dtot += __shfl_xor(dtot, 16);
    dtot += __shfl_xor(dtot, 32);
    const float invq = 1.0f / (dtot + 1e-9f);
    float invs[4];
    #pragma unroll
    for (int r = 0; r < 4; ++r) invs[r] = __shfl(invq, g * 4 + r);

    ushort_t* ob = ao + ((size_t)b * Tn + qt * 64 + w * 16) * Cn + h * 64;
    #pragma unroll
    for (int dt = 0; dt < 4; ++dt)
      #pragma unroll
      for (int r = 0; r < 4; ++r)
        ob[(size_t)(g * 4 + r) * Cn + dt * 16 + lcol] = f2bf(o[dt][r] * invs[r]);
  }
}

extern "C" void kernel_launch(void* const* d_in, const int* in_sizes, int n_in,
                              void* d_out, int out_size, void* d_ws, size_t ws_size,
                              hipStream_t stream) {
  const float* x         = (const float*)d_in[0];
  const float* attn_mask = (const float*)d_in[1];
  const float* lambda    = (const float*)d_in[2];
  const float* W_attn    = (const float*)d_in[3];
  const float* W_proj    = (const float*)d_in[4];
  float* out = (float*)d_out;

  const size_t nBTC = (size_t)Bn * Tn * Cn;        // 6.29M
  const size_t nW1  = (size_t)Cn * 3 * Cn;         // 1.77M
  const size_t nW2  = (size_t)Cn * Cn;             // 0.59M
  ushort_t* xh  = (ushort_t*)d_ws;
  ushort_t* xl  = xh + nBTC;
  ushort_t* WhT = xl + nBTC;
  ushort_t* WlT = WhT + nW1;
  ushort_t* WpT = WlT + nW1;
  ushort_t* qh  = WpT + nW2;
  ushort_t* ql  = qh + nBTC;
  ushort_t* kh  = ql + nBTC;
  ushort_t* kl  = kh + nBTC;
  ushort_t* vt  = kl + nBTC;
  ushort_t* ao  = xh;   // xh dead after qkv GEMM; reuse for attention output

  dim3 blk(256);

  prep_all<<<dim3(6720), blk, 0, stream>>>(
      x, xh, xl, W_attn, WhT, WlT, W_proj, WpT);

  gemm_qkv_fused<<<dim3(1248), blk, 0, stream>>>(
      xh, xl, WhT, WlT, lambda, attn_mask, qh, ql, kh, kl, vt);

  attn_mfma<<<dim3(768), blk, 0, stream>>>(
      qh, ql, kh, kl, vt, ao);

  gemm_proj<<<dim3(768), blk, 0, stream>>>(ao, WpT, out);
}